// Round 1
// 373.181 us; speedup vs baseline: 1.0524x; 1.0524x over previous
//
#include <hip/hip_runtime.h>

// Problem constants (fixed by the reference): B=8, S=512, D=384, VOCAB=50257.
#define BB 8
#define SS 512
#define DD 384
#define K2 (DD * DD)          // 147456 = flattened (d,e)
#define LCH 16                // list entries per pass (LDS-resident); observed total<=16
#define OT 4                  // o-rows per block: each LDS read-set feeds 4 Wc rows
#define KCH 8                 // k-chunks (grid.y)
#define NT 256                // 4 waves/block; 3 blocks/CU (LDS 48K) -> 12 waves/CU
#define GROUPS (K2 / 4)       // 36864 float4-groups over k
#define GPC (GROUPS / KCH)    // 4608 groups per chunk
#define ITERS (GPC / NT)      // 18
#define MAXL_CAP 1024

// ws layout: [0..16) count (int), [16..16400) list (ints), [16400..) u buffer
#define WS_LIST_OFF 16
#define WS_U_OFF 16400

// ---------------------------------------------------------------------------
// Kernel 1: flag positions s2 whose head s1 satisfies heads[b,s1]==0.
__global__ void flag_kernel(const int* __restrict__ heads, int* __restrict__ countp,
                            int* __restrict__ list, int maxl) {
    int b = blockIdx.x;
    int s2 = threadIdx.x;
    int h = heads[b * SS + s2];
    if (heads[b * SS + h] == 0) {
        int idx = atomicAdd(countp, 1);
        if (idx < maxl) list[idx] = b * SS + s2;
    }
}

// ---------------------------------------------------------------------------
// Recursive-halving cross-lane reduce: after all steps, lane L of the wave
// holds the 64-lane total of value index L. 63 shuffles total (vs 384 naive).
template <int HALF>
__device__ __forceinline__ void fold_step(float* red, int lane) {
#pragma unroll
    for (int i = 0; i < HALF; ++i) {
        float lo = red[i], hi = red[i + HALF];
        float send = (lane & HALF) ? lo : hi;
        float recv = __shfl_xor(send, HALF, 64);
        red[i] = (lane & HALF) ? (hi + recv) : (lo + recv);
    }
}

// ---------------------------------------------------------------------------
// Kernel 2: u[l,o] = sum_k p[l,k] * Wc[o,k], k = d*384+e, p = tok[l,d]*dep[l,e].
// Streams Wc once (226.5 MB -> ~34 us HBM floor). OT=4 halves LDS bytes per
// Wc byte vs OT=2: per-iter per-thread 64 B Wc vs 16*(4+16) B LDS.
// NT=256 + launch_bounds(256,3): 3 blocks/CU (LDS-capped), VGPR cap ~170 so
// acc[16][4] + 8 prefetch float4s fit without scratch spills.
__global__ __launch_bounds__(NT, 3) void bilinear_kernel(
    const float* __restrict__ Wc, const float* __restrict__ tok_table,
    const int* __restrict__ tokens, const int* __restrict__ list,
    const int* __restrict__ countp, float* __restrict__ u, int maxl) {
    __shared__ alignas(16) float tokS[LCH][DD];
    __shared__ alignas(16) float depS[LCH][DD];

    const int tid = threadIdx.x;
    const int lane = tid & 63;
    const int wid = tid >> 6;
    const int o0 = blockIdx.x * OT;          // 96 o-quads
    const int g0 = blockIdx.y * GPC;         // k-chunk base (float4 groups)

    int total = *countp;
    if (total > maxl) total = maxl;

    for (int cb = 0; cb < total; cb += LCH) {
        // ---- stage tok/dep rows into LDS (zero-padded)
        for (int idx = tid; idx < LCH * DD; idx += NT) {
            int l = idx / DD;
            int i = idx - l * DD;
            float t = 0.f;
            if (cb + l < total) {
                int pos = list[cb + l];
                t = tok_table[(size_t)tokens[pos] * DD + i];
            }
            tokS[l][i] = t;
            depS[l][i] = tanhf(t);           // t==0 -> dep==0 -> contributes 0
        }
        __syncthreads();

        const int lmax = total - cb;         // live entries this pass (wave-uniform)

        float acc[LCH][OT];
#pragma unroll
        for (int l = 0; l < LCH; ++l)
#pragma unroll
            for (int j = 0; j < OT; ++j) acc[l][j] = 0.f;

        // ---- prefetch iteration 0 (4 o-rows)
        const float* wbase = Wc + (size_t)o0 * K2;
        float4 wv[OT], nv[OT];
        {
            const float* wp = wbase + 4 * (size_t)(g0 + tid);
#pragma unroll
            for (int r = 0; r < OT; ++r) wv[r] = *(const float4*)(wp + (size_t)r * K2);
        }

#pragma unroll 1
        for (int it = 0; it < ITERS; ++it) {
            int gc = g0 + it * NT + tid;

            // prefetch next iteration before consuming current
#pragma unroll
            for (int r = 0; r < OT; ++r) nv[r] = make_float4(0.f, 0.f, 0.f, 0.f);
            if (it + 1 < ITERS) {
                const float* wp = wbase + 4 * (size_t)(gc + NT);
#pragma unroll
                for (int r = 0; r < OT; ++r) nv[r] = *(const float4*)(wp + (size_t)r * K2);
            }

            int d = gc / 96;                  // near-uniform across wave (<=2 values)
            int e4 = gc - d * 96;             // float4 index within dep row

#pragma unroll
            for (int l4 = 0; l4 < LCH / 4; ++l4) {
                if (l4 * 4 < lmax) {          // wave-uniform skip of dead 4-groups
#pragma unroll
                    for (int li = 0; li < 4; ++li) {
                        const int l = l4 * 4 + li;
                        float td = tokS[l][d];
                        float4 dv = *(const float4*)(&depS[l][e4 * 4]);
                        float px = td * dv.x, py = td * dv.y;
                        float pz = td * dv.z, pw = td * dv.w;
#pragma unroll
                        for (int r = 0; r < OT; ++r)
                            acc[l][r] += px * wv[r].x + py * wv[r].y +
                                         pz * wv[r].z + pw * wv[r].w;
                    }
                }
            }
#pragma unroll
            for (int r = 0; r < OT; ++r) wv[r] = nv[r];
        }

        // ---- fold-reduce all 64 (l,j) values across the wave (63 shuffles)
        float red[LCH * OT];
#pragma unroll
        for (int k = 0; k < LCH * OT; ++k) red[k] = acc[k >> 2][k & 3];
        fold_step<32>(red, lane);
        fold_step<16>(red, lane);
        fold_step<8>(red, lane);
        fold_step<4>(red, lane);
        fold_step<2>(red, lane);
        fold_step<1>(red, lane);
        // lane L now holds wave total for l=L>>2, j=L&3

        __syncthreads();                     // done reading tokS/depS
        float* redS = &tokS[0][0];           // reuse staging LDS: 4 waves x 64
        redS[wid * 64 + lane] = red[0];
        __syncthreads();
        if (tid < 64) {
            int l = tid >> 2, j = tid & 3;
            if (l < lmax) {
                float s = redS[tid] + redS[64 + tid] + redS[128 + tid] + redS[192 + tid];
                atomicAdd(&u[(size_t)(cb + l) * DD + o0 + j], s);
            }
        }
        __syncthreads();  // protect LDS before next chunk's staging
    }
}

// ---------------------------------------------------------------------------
// Kernel 3: output rows. Zeros are handled by a hipMemsetAsync on d_out before
// this launch; here only the ~1 heads==0 row per batch is computed. Grid = BB.
__global__ __launch_bounds__(SS) void finalize_kernel(
    const int* __restrict__ heads, const float* __restrict__ Wr,
    const float* __restrict__ bc, const float* __restrict__ br,
    const int* __restrict__ list, const int* __restrict__ countp,
    const float* __restrict__ u, float* __restrict__ out, int maxl) {
    int b = blockIdx.x;
    int tid = threadIdx.x;

    __shared__ float wpart[SS / 64];
    __shared__ int hitlist[64];
    __shared__ int nh;
    if (tid == 0) nh = 0;
    __syncthreads();

    // parallel sumw over Wr[0..511]
    float w = Wr[tid];
#pragma unroll
    for (int off = 32; off > 0; off >>= 1) w += __shfl_down(w, off, 64);
    if ((tid & 63) == 0) wpart[tid >> 6] = w;

    // collect this batch's output rows (heads[b,s1]==0); expected ~1
    if (heads[b * SS + tid] == 0) {
        int i = atomicAdd(&nh, 1);
        if (i < 64) hitlist[i] = tid;
    }
    __syncthreads();

    float sumw = 0.f;
#pragma unroll
    for (int q = 0; q < SS / 64; ++q) sumw += wpart[q];
    float brv = br[0];

    int total = *countp;
    if (total > maxl) total = maxl;
    int hn = nh;
    if (hn > 64) hn = 64;

    for (int i = 0; i < hn; ++i) {
        int s1 = hitlist[i];
        if (tid < DD) {
            int o = tid;
            float bco = bc[o];
            float t_off = tanhf(bco);
            float val = t_off * sumw + brv;
            for (int l = 0; l < total; ++l) {
                int pos = list[l];
                if ((pos >> 9) == b && heads[pos] == s1)
                    val += (tanhf(u[(size_t)l * DD + o] + bco) - t_off) * Wr[pos & 511];
            }
            out[(size_t)(b * SS + s1) * DD + o] = val;
        }
    }
}

// ---------------------------------------------------------------------------
extern "C" void kernel_launch(void* const* d_in, const int* in_sizes, int n_in,
                              void* d_out, int out_size, void* d_ws, size_t ws_size,
                              hipStream_t stream) {
    const int* tokens = (const int*)d_in[0];
    // d_in[1] = dep_types: computed-but-discarded in the reference (bug preserved)
    const int* heads = (const int*)d_in[2];
    const float* tok_table = (const float*)d_in[3];
    const float* Wc = (const float*)d_in[4];
    const float* bc = (const float*)d_in[5];
    const float* Wr = (const float*)d_in[6];
    const float* br = (const float*)d_in[7];
    float* out = (float*)d_out;

    char* ws = (char*)d_ws;
    int* countp = (int*)ws;
    int* list = (int*)(ws + WS_LIST_OFF);
    float* u = (float*)(ws + WS_U_OFF);

    long maxl_l = ((long)ws_size - WS_U_OFF) / (DD * 4);
    int maxl = maxl_l < 0 ? 0 : (maxl_l > MAXL_CAP ? MAXL_CAP : (int)maxl_l);

    // zero count + list + u scratch (harness poisons ws with 0xAA every call)
    hipMemsetAsync(d_ws, 0, (size_t)WS_U_OFF + (size_t)maxl * DD * 4, stream);
    // zero the whole output; finalize overwrites only live (heads==0) rows
    hipMemsetAsync(d_out, 0, (size_t)out_size, stream);

    flag_kernel<<<BB, SS, 0, stream>>>(heads, countp, list, maxl);
    bilinear_kernel<<<dim3(DD / OT, KCH), NT, 0, stream>>>(
        Wc, tok_table, tokens, list, countp, u, maxl);
    finalize_kernel<<<BB, SS, 0, stream>>>(
        heads, Wr, bc, br, list, countp, u, out, maxl);
}

// Round 2
// 370.128 us; speedup vs baseline: 1.0611x; 1.0082x over previous
//
#include <hip/hip_runtime.h>

// Problem constants (fixed by the reference): B=8, S=512, D=384, VOCAB=50257.
#define BB 8
#define SS 512
#define DD 384
#define D4 (DD / 4)           // 96 float4 per row
#define K2 (DD * DD)          // 147456 = flattened (d,e)
#define LCH 16                // list entries per pass (LDS-resident); observed total<=16
#define OT 4                  // o-rows per block: each LDS read-set feeds 4 Wc rows
#define KCH 8                 // k-chunks (grid.y); u holds KCH partials, plain stores
#define NT 256                // 4 waves/block; 3 blocks/CU (LDS 48K) -> 12 waves/CU
#define GROUPS (K2 / 4)       // 36864 float4-groups over k
#define GPC (GROUPS / KCH)    // 4608 groups per chunk
#define ITERS (GPC / NT)      // 18
#define MAXL_CAP 1024
#define PREP_NT 1024

// ws layout (bytes): [0,16) count | [16, 16+4*MAXL_CAP) list | tokW | depW | u
#define WS_LIST_OFF 16
#define WS_TOKW_OFF (WS_LIST_OFF + 4 * MAXL_CAP)   // 4112, 16B-aligned

// ---------------------------------------------------------------------------
// Kernel 1 (one block): build list of qualifying s2, then gather their tok
// rows and tanh ONCE into ws (previously every bilinear block re-gathered and
// re-tanh'd the same 16 rows: ~768x redundant).
__global__ __launch_bounds__(PREP_NT) void prep_kernel(
    const int* __restrict__ heads, const int* __restrict__ tokens,
    const float* __restrict__ tok_table, int* __restrict__ countp,
    int* __restrict__ list, float* __restrict__ tokW, float* __restrict__ depW,
    int maxl) {
    __shared__ int cnt;
    __shared__ int lst[MAXL_CAP];
    const int tid = threadIdx.x;
    if (tid == 0) cnt = 0;
    __syncthreads();

    for (int pos = tid; pos < BB * SS; pos += PREP_NT) {
        int h = heads[pos];
        if (heads[(pos & ~(SS - 1)) + h] == 0) {
            int i = atomicAdd(&cnt, 1);
            if (i < maxl) lst[i] = pos;
        }
    }
    __syncthreads();

    int total = cnt;
    if (total > maxl) total = maxl;
    if (tid == 0) *countp = total;
    for (int i = tid; i < total; i += PREP_NT) list[i] = lst[i];

    // gather + tanh (total*384 elems; ~6 per thread for total~16)
    for (int idx = tid; idx < total * DD; idx += PREP_NT) {
        int l = idx / DD;
        int i = idx - l * DD;
        float t = tok_table[(size_t)tokens[lst[l]] * DD + i];
        tokW[idx] = t;
        depW[idx] = tanhf(t);
    }
}

// ---------------------------------------------------------------------------
// Recursive-halving cross-lane reduce: after all steps, lane L of the wave
// holds the 64-lane total of value index L. 63 shuffles total.
template <int HALF>
__device__ __forceinline__ void fold_step(float* red, int lane) {
#pragma unroll
    for (int i = 0; i < HALF; ++i) {
        float lo = red[i], hi = red[i + HALF];
        float send = (lane & HALF) ? lo : hi;
        float recv = __shfl_xor(send, HALF, 64);
        red[i] = (lane & HALF) ? (hi + recv) : (lo + recv);
    }
}

// ---------------------------------------------------------------------------
// Kernel 2: u[c,l,o] = partial_k p[l,k]*Wc[o,k] over k-chunk c.
// Streams Wc once (226.5 MB -> ~34 us HBM floor). Staging is now 12 coalesced
// float4 copies from prep's tokW/depW (no gather, no tanh). Plain stores to
// per-chunk u partials: no atomics, no u memset needed.
__global__ __launch_bounds__(NT, 3) void bilinear_kernel(
    const float* __restrict__ Wc, const float* __restrict__ tokW,
    const float* __restrict__ depW, const int* __restrict__ countp,
    float* __restrict__ u, int maxl) {
    __shared__ alignas(16) float tokS[LCH][DD];
    __shared__ alignas(16) float depS[LCH][DD];

    const int tid = threadIdx.x;
    const int lane = tid & 63;
    const int wid = tid >> 6;
    const int o0 = blockIdx.x * OT;          // 96 o-quads
    const int g0 = blockIdx.y * GPC;         // k-chunk base (float4 groups)

    int total = *countp;
    if (total > maxl) total = maxl;

    for (int cb = 0; cb < total; cb += LCH) {
        // ---- stage: coalesced float4 copies, zero-pad dead rows
        {
            const float4* tw = (const float4*)tokW;
            const float4* dw = (const float4*)depW;
            float4* ts = (float4*)&tokS[0][0];
            float4* ds = (float4*)&depS[0][0];
            const float4 z = make_float4(0.f, 0.f, 0.f, 0.f);
            for (int idx = tid; idx < LCH * D4; idx += NT) {
                int l = idx / D4;
                bool live = (cb + l) < total;
                int src = cb * D4 + idx;      // (cb+l)*D4 + i4
                ts[idx] = live ? tw[src] : z;
                ds[idx] = live ? dw[src] : z;
            }
        }
        __syncthreads();

        const int lmax = total - cb;         // live entries this pass (wave-uniform)

        float acc[LCH][OT];
#pragma unroll
        for (int l = 0; l < LCH; ++l)
#pragma unroll
            for (int j = 0; j < OT; ++j) acc[l][j] = 0.f;

        // ---- prefetch iteration 0 (4 o-rows)
        const float* wbase = Wc + (size_t)o0 * K2;
        float4 wv[OT], nv[OT];
        {
            const float* wp = wbase + 4 * (size_t)(g0 + tid);
#pragma unroll
            for (int r = 0; r < OT; ++r) wv[r] = *(const float4*)(wp + (size_t)r * K2);
        }

#pragma unroll 1
        for (int it = 0; it < ITERS; ++it) {
            int gc = g0 + it * NT + tid;

            // prefetch next iteration; clamp addr on last iter (loads stay valid,
            // values unused) to avoid a branch + zero-init
            {
                int gn = (it + 1 < ITERS) ? (gc + NT) : (g0 + tid);
                const float* wp = wbase + 4 * (size_t)gn;
#pragma unroll
                for (int r = 0; r < OT; ++r) nv[r] = *(const float4*)(wp + (size_t)r * K2);
            }

            int d = gc / 96;                  // near-uniform across wave (<=3 values)
            int e4 = gc - d * 96;             // float4 index within dep row

#pragma unroll
            for (int l4 = 0; l4 < LCH / 4; ++l4) {
                if (l4 * 4 < lmax) {          // wave-uniform skip of dead 4-groups
#pragma unroll
                    for (int li = 0; li < 4; ++li) {
                        const int l = l4 * 4 + li;
                        float td = tokS[l][d];
                        float4 dv = *(const float4*)(&depS[l][e4 * 4]);
                        float px = td * dv.x, py = td * dv.y;
                        float pz = td * dv.z, pw = td * dv.w;
#pragma unroll
                        for (int r = 0; r < OT; ++r)
                            acc[l][r] += px * wv[r].x + py * wv[r].y +
                                         pz * wv[r].z + pw * wv[r].w;
                    }
                }
            }
#pragma unroll
            for (int r = 0; r < OT; ++r) wv[r] = nv[r];
        }

        // ---- fold-reduce all 64 (l,j) values across the wave (63 shuffles)
        float red[LCH * OT];
#pragma unroll
        for (int k = 0; k < LCH * OT; ++k) red[k] = acc[k >> 2][k & 3];
        fold_step<32>(red, lane);
        fold_step<16>(red, lane);
        fold_step<8>(red, lane);
        fold_step<4>(red, lane);
        fold_step<2>(red, lane);
        fold_step<1>(red, lane);
        // lane L now holds wave total for l=L>>2, j=L&3

        __syncthreads();                     // done reading tokS/depS
        float* redS = &tokS[0][0];           // reuse staging LDS: 4 waves x 64
        redS[wid * 64 + lane] = red[0];
        __syncthreads();
        if (tid < 64) {
            int l = tid >> 2, j = tid & 3;
            if (l < lmax && l < LCH) {
                float s = redS[tid] + redS[64 + tid] + redS[128 + tid] + redS[192 + tid];
                // plain store: (chunk, list-row, o) partial
                u[((size_t)blockIdx.y * maxl + (cb + l)) * DD + o0 + j] = s;
            }
        }
        __syncthreads();  // protect LDS before next chunk's staging
    }
}

// ---------------------------------------------------------------------------
// Kernel 3: output rows. Zeros handled by hipMemsetAsync on d_out; here only
// the ~1 heads==0 row per batch is computed. Grid = BB. Sums KCH u-partials.
__global__ __launch_bounds__(SS) void finalize_kernel(
    const int* __restrict__ heads, const float* __restrict__ Wr,
    const float* __restrict__ bc, const float* __restrict__ br,
    const int* __restrict__ list, const int* __restrict__ countp,
    const float* __restrict__ u, float* __restrict__ out, int maxl) {
    int b = blockIdx.x;
    int tid = threadIdx.x;

    __shared__ float wpart[SS / 64];
    __shared__ int hitlist[64];
    __shared__ int nh;
    if (tid == 0) nh = 0;
    __syncthreads();

    // parallel sumw over Wr[0..511]
    float w = Wr[tid];
#pragma unroll
    for (int off = 32; off > 0; off >>= 1) w += __shfl_down(w, off, 64);
    if ((tid & 63) == 0) wpart[tid >> 6] = w;

    // collect this batch's output rows (heads[b,s1]==0); expected ~1
    if (heads[b * SS + tid] == 0) {
        int i = atomicAdd(&nh, 1);
        if (i < 64) hitlist[i] = tid;
    }
    __syncthreads();

    float sumw = 0.f;
#pragma unroll
    for (int q = 0; q < SS / 64; ++q) sumw += wpart[q];
    float brv = br[0];

    int total = *countp;
    if (total > maxl) total = maxl;
    int hn = nh;
    if (hn > 64) hn = 64;

    for (int i = 0; i < hn; ++i) {
        int s1 = hitlist[i];
        if (tid < DD) {
            int o = tid;
            float bco = bc[o];
            float t_off = tanhf(bco);
            float val = t_off * sumw + brv;
            for (int l = 0; l < total; ++l) {
                int pos = list[l];
                if ((pos >> 9) == b && heads[pos] == s1) {
                    float sum = 0.f;
#pragma unroll
                    for (int c = 0; c < KCH; ++c)
                        sum += u[((size_t)c * maxl + l) * DD + o];
                    val += (tanhf(sum + bco) - t_off) * Wr[pos & 511];
                }
            }
            out[(size_t)(b * SS + s1) * DD + o] = val;
        }
    }
}

// ---------------------------------------------------------------------------
extern "C" void kernel_launch(void* const* d_in, const int* in_sizes, int n_in,
                              void* d_out, int out_size, void* d_ws, size_t ws_size,
                              hipStream_t stream) {
    const int* tokens = (const int*)d_in[0];
    // d_in[1] = dep_types: computed-but-discarded in the reference (bug preserved)
    const int* heads = (const int*)d_in[2];
    const float* tok_table = (const float*)d_in[3];
    const float* Wc = (const float*)d_in[4];
    const float* bc = (const float*)d_in[5];
    const float* Wr = (const float*)d_in[6];
    const float* br = (const float*)d_in[7];
    float* out = (float*)d_out;

    char* ws = (char*)d_ws;
    int* countp = (int*)ws;
    int* list = (int*)(ws + WS_LIST_OFF);

    // per-row bytes: tokW + depW + KCH partials
    long avail = (long)ws_size - WS_TOKW_OFF;
    long per_row = (long)(2 + KCH) * DD * 4;   // 15360
    long maxl_l = avail / per_row;
    int maxl = maxl_l < 0 ? 0 : (maxl_l > MAXL_CAP ? MAXL_CAP : (int)maxl_l);

    float* tokW = (float*)(ws + WS_TOKW_OFF);
    float* depW = tokW + (size_t)maxl * DD;
    float* u = depW + (size_t)maxl * DD;

    // zero the whole output; finalize overwrites only live (heads==0) rows.
    // No ws memset needed: prep writes count/list, bilinear writes u before read.
    hipMemsetAsync(d_out, 0, (size_t)out_size, stream);

    prep_kernel<<<1, PREP_NT, 0, stream>>>(heads, tokens, tok_table,
                                           countp, list, tokW, depW, maxl);
    bilinear_kernel<<<dim3(DD / OT, KCH), NT, 0, stream>>>(
        Wc, tokW, depW, countp, u, maxl);
    finalize_kernel<<<BB, SS, 0, stream>>>(
        heads, Wr, bc, br, list, countp, u, out, maxl);
}